// Round 1
// baseline (969.595 us; speedup 1.0000x reference)
//
#include <hip/hip_runtime.h>
#include <hip/hip_bf16.h>
#include <cstddef>

typedef __bf16 bf16x8 __attribute__((ext_vector_type(8)));
typedef __bf16 bf16x4 __attribute__((ext_vector_type(4)));
typedef float f32x4 __attribute__((ext_vector_type(4)));

#define MFMA16(a, b, c) __builtin_amdgcn_mfma_f32_16x16x32_bf16((a), (b), (c), 0, 0, 0)

// ---------------- fp32 -> bf16 convert (X_q, X_k, X_v) ----------------
__global__ __launch_bounds__(256) void cvt3(const float* __restrict__ a,
                                            const float* __restrict__ b,
                                            const float* __restrict__ c,
                                            __bf16* __restrict__ oa,
                                            __bf16* __restrict__ ob,
                                            __bf16* __restrict__ oc) {
  const float* src = blockIdx.y == 0 ? a : (blockIdx.y == 1 ? b : c);
  __bf16* dst = blockIdx.y == 0 ? oa : (blockIdx.y == 1 ? ob : oc);
  const size_t i = ((size_t)blockIdx.x * 256 + threadIdx.x) * 4;
  float4 v = *(const float4*)(src + i);
  bf16x4 o = {(__bf16)v.x, (__bf16)v.y, (__bf16)v.z, (__bf16)v.w};
  *(bf16x4*)(dst + i) = o;
}

// ---------------- W [in][out] fp32 -> W^T [out][in] bf16 ----------------
__global__ __launch_bounds__(256) void twt(const float* __restrict__ w0, const float* __restrict__ w1,
                                           const float* __restrict__ w2, const float* __restrict__ w3,
                                           __bf16* __restrict__ o0, __bf16* __restrict__ o1,
                                           __bf16* __restrict__ o2, __bf16* __restrict__ o3) {
  const float* W;
  __bf16* O;
  switch (blockIdx.z) {
    case 0: W = w0; O = o0; break;
    case 1: W = w1; O = o1; break;
    case 2: W = w2; O = o2; break;
    default: W = w3; O = o3; break;
  }
  __shared__ float t[32][33];
  const int tx = threadIdx.x & 31, ty = threadIdx.x >> 5;
  const int bx = blockIdx.x * 32, by = blockIdx.y * 32;
#pragma unroll
  for (int i = 0; i < 4; ++i)
    t[ty + 8 * i][tx] = W[(size_t)(by + ty + 8 * i) * 1024 + bx + tx];
  __syncthreads();
#pragma unroll
  for (int i = 0; i < 4; ++i)
    O[(size_t)(bx + ty + 8 * i) * 1024 + by + tx] = (__bf16)t[tx][ty + 8 * i];
}

// ---------------- C = A @ B^T   (A: MxK bf16 row-major, B: NxK bf16 row-major) ---
// M = 4096 (grid.y*128), N = 1024, K = 1024. 128x128 tile, 4 waves, each wave 64x64.
template <bool OUT_BF16>
__global__ __launch_bounds__(256) void gemm_bt(const __bf16* __restrict__ A,
                                               const __bf16* __restrict__ B,
                                               void* __restrict__ Cout,
                                               const float* __restrict__ bias,
                                               float scale) {
  constexpr int K = 1024, N = 1024;
  const int tid = threadIdx.x, wave = tid >> 6, lane = tid & 63;
  const int qd = lane >> 4, ln = lane & 15;
  const int m0 = blockIdx.y * 128, n0 = blockIdx.x * 128;
  const int wr = wave >> 1, wc = wave & 1;

  __shared__ __align__(16) __bf16 sA[128][40];
  __shared__ __align__(16) __bf16 sB[128][40];

  f32x4 acc[4][4] = {};

  const int srow = tid >> 2, sch = (tid & 3) * 8;

  for (int k0 = 0; k0 < K; k0 += 32) {
    __syncthreads();
    *(bf16x8*)&sA[srow][sch]      = *(const bf16x8*)(A + (size_t)(m0 + srow) * K + k0 + sch);
    *(bf16x8*)&sA[srow + 64][sch] = *(const bf16x8*)(A + (size_t)(m0 + srow + 64) * K + k0 + sch);
    *(bf16x8*)&sB[srow][sch]      = *(const bf16x8*)(B + (size_t)(n0 + srow) * K + k0 + sch);
    *(bf16x8*)&sB[srow + 64][sch] = *(const bf16x8*)(B + (size_t)(n0 + srow + 64) * K + k0 + sch);
    __syncthreads();

    bf16x8 af[4], bfv[4];
#pragma unroll
    for (int i = 0; i < 4; ++i) af[i] = *(const bf16x8*)&sA[wr * 64 + i * 16 + ln][qd * 8];
#pragma unroll
    for (int j = 0; j < 4; ++j) bfv[j] = *(const bf16x8*)&sB[wc * 64 + j * 16 + ln][qd * 8];
#pragma unroll
    for (int i = 0; i < 4; ++i)
#pragma unroll
      for (int j = 0; j < 4; ++j) acc[i][j] = MFMA16(af[i], bfv[j], acc[i][j]);
  }

#pragma unroll
  for (int i = 0; i < 4; ++i)
#pragma unroll
    for (int j = 0; j < 4; ++j)
#pragma unroll
      for (int r = 0; r < 4; ++r) {
        const int row = m0 + wr * 64 + i * 16 + qd * 4 + r;
        const int col = n0 + wc * 64 + j * 16 + ln;
        float v = acc[i][j][r] * scale;
        if (bias) v += bias[col];
        if (OUT_BF16)
          ((__bf16*)Cout)[(size_t)row * N + col] = (__bf16)v;
        else
          ((float*)Cout)[(size_t)row * N + col] = v;
      }
}

// ---------------- fused sigmoid attention per (q-tile, head, batch) ----------------
// Q pre-scaled by 1/8. S-tile 128x128 per iter; A written fp32 to d_out; H accumulated.
__global__ __launch_bounds__(256) void attn(const __bf16* __restrict__ Q,
                                            const __bf16* __restrict__ Kb,
                                            const __bf16* __restrict__ Vb,
                                            float* __restrict__ Aout,
                                            __bf16* __restrict__ Hc) {
  const int qt = blockIdx.x, h = blockIdx.y, b = blockIdx.z;
  const int tid = threadIdx.x, wave = tid >> 6, lane = tid & 63;
  const int qd = lane >> 4, ln = lane & 15;
  const int q0 = qt * 128;
  const int wr = wave >> 1, wc = wave & 1;

  __shared__ __align__(16) __bf16 sQ[128][72];
  __shared__ __align__(16) __bf16 sVt[64][136];
  // aliased buffer: K-tile with row stride 72, then A-tile (bf16) with row stride 136
  __shared__ __align__(16) __bf16 sKA[128 * 136];

  const __bf16* Qg = Q + (size_t)(b * 2048 + q0) * 1024 + h * 64;
#pragma unroll
  for (int p = 0; p < 4; ++p) {
    const int idx = p * 256 + tid, row = idx >> 3, ch = (idx & 7) * 8;
    *(bf16x8*)&sQ[row][ch] = *(const bf16x8*)(Qg + (size_t)row * 1024 + ch);
  }

  f32x4 hacc[2][4] = {};

  for (int kt = 0; kt < 16; ++kt) {
    const int k0 = kt * 128;
    __syncthreads();  // prev iter's sKA/sVt consumers done; also covers sQ on kt==0

    const __bf16* Kg = Kb + (size_t)(b * 2048 + k0) * 1024 + h * 64;
    const __bf16* Vg = Vb + (size_t)(b * 2048 + k0) * 1024 + h * 64;
#pragma unroll
    for (int p = 0; p < 4; ++p) {
      const int idx = p * 256 + tid, row = idx >> 3, ch = (idx & 7) * 8;
      *(bf16x8*)&sKA[row * 72 + ch] = *(const bf16x8*)(Kg + (size_t)row * 1024 + ch);
      bf16x8 v = *(const bf16x8*)(Vg + (size_t)row * 1024 + ch);
#pragma unroll
      for (int e = 0; e < 8; ++e) sVt[ch + e][row] = v[e];
    }
    __syncthreads();

    // S = Q·K^T : wave quadrant (wr rows 64, wc cols 64)
    f32x4 sacc[4][4] = {};
#pragma unroll
    for (int ks = 0; ks < 64; ks += 32) {
      bf16x8 af[4], bfv[4];
#pragma unroll
      for (int i = 0; i < 4; ++i) af[i] = *(const bf16x8*)&sQ[wr * 64 + i * 16 + ln][ks + qd * 8];
#pragma unroll
      for (int j = 0; j < 4; ++j)
        bfv[j] = *(const bf16x8*)&sKA[(wc * 64 + j * 16 + ln) * 72 + ks + qd * 8];
#pragma unroll
      for (int i = 0; i < 4; ++i)
#pragma unroll
        for (int j = 0; j < 4; ++j) sacc[i][j] = MFMA16(af[i], bfv[j], sacc[i][j]);
    }
    __syncthreads();  // all waves done reading K-tile before aliasing as A-tile

    // sigmoid -> bf16 A tile in sKA (stride 136)
#pragma unroll
    for (int i = 0; i < 4; ++i)
#pragma unroll
      for (int j = 0; j < 4; ++j)
#pragma unroll
        for (int r = 0; r < 4; ++r) {
          const float s = sacc[i][j][r];
          const float a = 1.0f / (1.0f + __expf(-s));
          const int rr = wr * 64 + i * 16 + qd * 4 + r;
          const int cc = wc * 64 + j * 16 + ln;
          sKA[rr * 136 + cc] = (__bf16)a;
        }
    __syncthreads();

    // coalesced fp32 A write from LDS
    {
      float* Ag = Aout + ((size_t)((b * 16 + h) * 2048 + q0)) * 2048 + k0;
      const int row = tid >> 1, cb = (tid & 1) * 64;
#pragma unroll
      for (int c = 0; c < 64; c += 8) {
        bf16x8 v8 = *(const bf16x8*)&sKA[row * 136 + cb + c];
        float4 f0 = {(float)v8[0], (float)v8[1], (float)v8[2], (float)v8[3]};
        float4 f1 = {(float)v8[4], (float)v8[5], (float)v8[6], (float)v8[7]};
        *(float4*)(Ag + (size_t)row * 2048 + cb + c) = f0;
        *(float4*)(Ag + (size_t)row * 2048 + cb + c + 4) = f1;
      }
    }

    // H += A·V (wave owns rows 32*wave .. +31, all 64 cols)
#pragma unroll
    for (int ks = 0; ks < 128; ks += 32) {
      bf16x8 af[2], bfv[4];
#pragma unroll
      for (int i = 0; i < 2; ++i)
        af[i] = *(const bf16x8*)&sKA[(wave * 32 + i * 16 + ln) * 136 + ks + qd * 8];
#pragma unroll
      for (int j = 0; j < 4; ++j) bfv[j] = *(const bf16x8*)&sVt[j * 16 + ln][ks + qd * 8];
#pragma unroll
      for (int i = 0; i < 2; ++i)
#pragma unroll
        for (int j = 0; j < 4; ++j) hacc[i][j] = MFMA16(af[i], bfv[j], hacc[i][j]);
    }
  }

  __bf16* Hg = Hc + (size_t)(b * 2048 + q0) * 1024 + h * 64;
#pragma unroll
  for (int i = 0; i < 2; ++i)
#pragma unroll
    for (int j = 0; j < 4; ++j)
#pragma unroll
      for (int r = 0; r < 4; ++r)
        Hg[(size_t)(wave * 32 + i * 16 + qd * 4 + r) * 1024 + j * 16 + ln] = (__bf16)hacc[i][j][r];
}

extern "C" void kernel_launch(void* const* d_in, const int* in_sizes, int n_in,
                              void* d_out, int out_size, void* d_ws, size_t ws_size,
                              hipStream_t stream) {
  const float* Xq = (const float*)d_in[0];
  const float* Xk = (const float*)d_in[1];
  const float* Xv = (const float*)d_in[2];
  const float* Wq = (const float*)d_in[3];
  const float* Wk = (const float*)d_in[4];
  const float* Wv = (const float*)d_in[5];
  const float* Wh = (const float*)d_in[6];
  const float* bh = (const float*)d_in[7];

  float* Hout = (float*)d_out;               // 4096 x 1024 fp32
  float* Aout = Hout + (size_t)4096 * 1024;  // 2 x 16 x 2048 x 2048 fp32

  // workspace layout (bf16)
  __bf16* p = (__bf16*)d_ws;
  __bf16* Xq_bf = p; p += (size_t)4096 * 1024;
  __bf16* Xk_bf = p; p += (size_t)4096 * 1024;
  __bf16* Xv_bf = p; p += (size_t)4096 * 1024;
  __bf16* WqT = p; p += (size_t)1024 * 1024;
  __bf16* WkT = p; p += (size_t)1024 * 1024;
  __bf16* WvT = p; p += (size_t)1024 * 1024;
  __bf16* WhT = p; p += (size_t)1024 * 1024;
  __bf16* Qb = p; p += (size_t)4096 * 1024;
  __bf16* Kb = p; p += (size_t)4096 * 1024;
  __bf16* Vb = p; p += (size_t)4096 * 1024;
  __bf16* Hc = p; p += (size_t)4096 * 1024;

  cvt3<<<dim3(4096, 3), 256, 0, stream>>>(Xq, Xk, Xv, Xq_bf, Xk_bf, Xv_bf);
  twt<<<dim3(32, 32, 4), 256, 0, stream>>>(Wq, Wk, Wv, Wh, WqT, WkT, WvT, WhT);

  // Q gets the 1/sqrt(dk) = 0.125 scale fused in
  gemm_bt<true><<<dim3(8, 32), 256, 0, stream>>>(Xq_bf, WqT, (void*)Qb, nullptr, 0.125f);
  gemm_bt<true><<<dim3(8, 32), 256, 0, stream>>>(Xk_bf, WkT, (void*)Kb, nullptr, 1.0f);
  gemm_bt<true><<<dim3(8, 32), 256, 0, stream>>>(Xv_bf, WvT, (void*)Vb, nullptr, 1.0f);

  attn<<<dim3(16, 16, 2), 256, 0, stream>>>(Qb, Kb, Vb, Aout, Hc);

  gemm_bt<false><<<dim3(8, 32), 256, 0, stream>>>(Hc, WhT, (void*)Hout, bh, 1.0f);
}